// Round 1
// baseline (101.800 us; speedup 1.0000x reference)
//
#include <hip/hip_runtime.h>
#include <cstdint>
#include <cstddef>

#define BD 16
#define SD 4096
#define DD 1024
#define L2E 1.4426950408889634f

__device__ __forceinline__ float dot4(float4 a, float4 b) {
    return fmaf(a.x, b.x, fmaf(a.y, b.y, fmaf(a.z, b.z, a.w * b.w)));
}
__device__ __forceinline__ void fma4(float4& o, float p, float4 v) {
    o.x = fmaf(p, v.x, o.x); o.y = fmaf(p, v.y, o.y);
    o.z = fmaf(p, v.z, o.z); o.w = fmaf(p, v.w, o.w);
}
__device__ __forceinline__ void mul4(float4& o, float c) {
    o.x *= c; o.y *= c; o.z *= c; o.w *= c;
}
__device__ __forceinline__ void add4(float4& a, float4 b) {
    a.x += b.x; a.y += b.y; a.z += b.z; a.w += b.w;
}

// ---------------------------------------------------------------------------
// Kernel 1: ctil[b,d] = sum_e ctx[b,e] * W[e,d]
// grid (4 d-tiles, 16 b, 4 e-chunks), 256 threads. Partial sums via atomicAdd.
// ---------------------------------------------------------------------------
__global__ void ctx_proj_kernel(const float* __restrict__ ctx,
                                const float* __restrict__ W,
                                float* __restrict__ ctil) {
    const int tid = threadIdx.x;          // 0..255
    const int dt  = blockIdx.x;           // 0..3
    const int b   = blockIdx.y;           // 0..15
    const int ez  = blockIdx.z;           // 0..3
    const int d   = dt * 256 + tid;

    __shared__ float cs[256];
    cs[tid] = ctx[b * DD + ez * 256 + tid];
    __syncthreads();

    float acc = 0.f;
    const float* Wp = W + (size_t)(ez * 256) * DD + d;
#pragma unroll 8
    for (int e = 0; e < 256; ++e) {
        acc = fmaf(cs[e], Wp[(size_t)e * DD], acc);
    }
    atomicAdd(&ctil[b * DD + d], acc);
}

// ---------------------------------------------------------------------------
// Kernel 2: fused score + online-softmax + weighted accumulation.
// One pass over values. grid (nchunk, B), 256 threads = 4 waves.
// Each wave: rows i = wave, wave+4, ... within the chunk; keeps running
// (m, l, o[1024]) with o spread 16 f32/lane as 4x float4.
// Block partial (o[1024], m, l) -> workspace record of 1028 floats.
// ---------------------------------------------------------------------------
__global__ __launch_bounds__(256)
void flash_kernel(const float* __restrict__ values,
                  const float* __restrict__ ctil,
                  float* __restrict__ partials,
                  int nchunk) {
    const int chunk = blockIdx.x;
    const int b     = blockIdx.y;
    const int rows  = SD / nchunk;
    const int r0    = chunk * rows;
    const int tid   = threadIdx.x;
    const int wave  = tid >> 6;
    const int lane  = tid & 63;

    const float4* ct4 = (const float4*)(ctil + (size_t)b * DD);
    const float4 c0 = ct4[lane];
    const float4 c1 = ct4[64 + lane];
    const float4 c2 = ct4[128 + lane];
    const float4 c3 = ct4[192 + lane];

    float4 o0 = {0.f, 0.f, 0.f, 0.f}, o1 = o0, o2 = o0, o3 = o0;
    float m = -1e30f, l = 0.f;

    for (int i = wave; i < rows; i += 4) {
        const float4* v4 = (const float4*)(values + ((size_t)b * SD + r0 + i) * DD);
        float4 v0 = v4[lane];
        float4 v1 = v4[64 + lane];
        float4 v2 = v4[128 + lane];
        float4 v3 = v4[192 + lane];

        float s = dot4(v0, c0) + dot4(v1, c1) + dot4(v2, c2) + dot4(v3, c3);
#pragma unroll
        for (int off = 32; off > 0; off >>= 1) s += __shfl_xor(s, off, 64);

        if (s > m) {  // rescale only when the running max moves (rare)
            float corr = exp2f((m - s) * L2E);
            m = s;
            l *= corr;
            mul4(o0, corr); mul4(o1, corr); mul4(o2, corr); mul4(o3, corr);
        }
        float p = exp2f((s - m) * L2E);
        l += p;
        fma4(o0, p, v0); fma4(o1, p, v1); fma4(o2, p, v2); fma4(o3, p, v3);
    }

    // ---- combine the 4 waves' partials ----
    __shared__ float red_m[4];
    __shared__ float red_l[4];
    __shared__ float obuf[DD];

    if (lane == 0) { red_m[wave] = m; red_l[wave] = l; }
    __syncthreads();

    const float M = fmaxf(fmaxf(red_m[0], red_m[1]), fmaxf(red_m[2], red_m[3]));
    const float Lb =
        red_l[0] * exp2f((red_m[0] - M) * L2E) +
        red_l[1] * exp2f((red_m[1] - M) * L2E) +
        red_l[2] * exp2f((red_m[2] - M) * L2E) +
        red_l[3] * exp2f((red_m[3] - M) * L2E);

    const float corr = exp2f((m - M) * L2E);  // wave-uniform
    mul4(o0, corr); mul4(o1, corr); mul4(o2, corr); mul4(o3, corr);

    float4* ob4 = (float4*)obuf;
    for (int w = 0; w < 4; ++w) {
        if (wave == w) {
            if (w == 0) {
                ob4[lane] = o0; ob4[64 + lane] = o1;
                ob4[128 + lane] = o2; ob4[192 + lane] = o3;
            } else {
                float4 t;
                t = ob4[lane];       add4(t, o0); ob4[lane] = t;
                t = ob4[64 + lane];  add4(t, o1); ob4[64 + lane] = t;
                t = ob4[128 + lane]; add4(t, o2); ob4[128 + lane] = t;
                t = ob4[192 + lane]; add4(t, o3); ob4[192 + lane] = t;
            }
        }
        __syncthreads();
    }

    float* part = partials + (size_t)(b * nchunk + chunk) * 1028;
    ((float4*)part)[tid] = ob4[tid];
    if (tid == 0) { part[1024] = M; part[1025] = Lb; }
}

// ---------------------------------------------------------------------------
// Kernel 3: per-batch combine of nchunk partials -> out[b, :]
// grid B, 256 threads.
// ---------------------------------------------------------------------------
__global__ void finalize_kernel(const float* __restrict__ partials,
                                float* __restrict__ out,
                                int nchunk) {
    const int b   = blockIdx.x;
    const int tid = threadIdx.x;
    const float* base = partials + (size_t)b * nchunk * 1028;

    __shared__ float corr_s[64];
    __shared__ float L_s;

    if (tid == 0) {
        float M = -1e30f;
        for (int i = 0; i < nchunk; ++i) M = fmaxf(M, base[(size_t)i * 1028 + 1024]);
        float L = 0.f;
        for (int i = 0; i < nchunk; ++i) {
            float c = exp2f((base[(size_t)i * 1028 + 1024] - M) * L2E);
            corr_s[i] = c;
            L = fmaf(c, base[(size_t)i * 1028 + 1025], L);
        }
        L_s = L;
    }
    __syncthreads();

    const float inv = 1.0f / L_s;
#pragma unroll
    for (int d = tid; d < DD; d += 256) {
        float acc = 0.f;
        for (int i = 0; i < nchunk; ++i) {
            acc = fmaf(corr_s[i], base[(size_t)i * 1028 + d], acc);
        }
        out[(size_t)b * DD + d] = acc * inv;
    }
}

// ---------------------------------------------------------------------------
extern "C" void kernel_launch(void* const* d_in, const int* in_sizes, int n_in,
                              void* d_out, int out_size, void* d_ws, size_t ws_size,
                              hipStream_t stream) {
    const float* values = (const float*)d_in[0];   // [B,S,D]
    const float* ctx    = (const float*)d_in[1];   // [B,D]
    const float* W      = (const float*)d_in[2];   // [D,D]
    // d_in[3] = bias: cancels exactly in softmax (per-batch constant shift).
    float* out = (float*)d_out;                    // [B,D] f32

    float* ctil     = (float*)d_ws;                // B*D floats
    float* partials = ctil + (size_t)BD * DD;      // B*nchunk*1028 floats

    int nchunk = 64;
    for (;;) {
        size_t need = (size_t)BD * DD * 4 + (size_t)BD * nchunk * 1028 * 4;
        if (need <= ws_size || nchunk == 1) break;
        nchunk >>= 1;
    }

    hipMemsetAsync(ctil, 0, (size_t)BD * DD * sizeof(float), stream);
    ctx_proj_kernel<<<dim3(4, BD, 4), 256, 0, stream>>>(ctx, W, ctil);
    flash_kernel<<<dim3(nchunk, BD), 256, 0, stream>>>(values, ctil, partials, nchunk);
    finalize_kernel<<<BD, 256, 0, stream>>>(partials, out, nchunk);
}

// Round 2
// 73.729 us; speedup vs baseline: 1.3807x; 1.3807x over previous
//
#include <hip/hip_runtime.h>
#include <cstdint>
#include <cstddef>

#define BD 16
#define SD 4096
#define DD 1024
#define L2E 1.4426950408889634f
#define PREC 1028   // floats per partial record: 1024 o + m + l + pad

__device__ __forceinline__ float dot4(float4 a, float4 b) {
    return fmaf(a.x, b.x, fmaf(a.y, b.y, fmaf(a.z, b.z, a.w * b.w)));
}
__device__ __forceinline__ void fma4(float4& o, float p, float4 v) {
    o.x = fmaf(p, v.x, o.x); o.y = fmaf(p, v.y, o.y);
    o.z = fmaf(p, v.z, o.z); o.w = fmaf(p, v.w, o.w);
}
__device__ __forceinline__ void mul4(float4& o, float c) {
    o.x *= c; o.y *= c; o.z *= c; o.w *= c;
}
__device__ __forceinline__ void add4(float4& a, float4 b) {
    a.x += b.x; a.y += b.y; a.z += b.z; a.w += b.w;
}

// ---------------------------------------------------------------------------
// Kernel 1: ctil[b,d] = sum_e ctx[b,e] * W[e,d]  (bias dropped: softmax-shift
// invariant). Atomic-free: grid (16 d-tiles, 16 b) = 256 blocks; 256 threads
// = 64 d-lanes x 4 e-groups; LDS tree-reduce over the 4 groups.
// ---------------------------------------------------------------------------
__global__ __launch_bounds__(256)
void ctx_proj_kernel(const float* __restrict__ ctx,
                     const float* __restrict__ W,
                     float* __restrict__ ctil) {
    const int tid = threadIdx.x;
    const int dl  = tid & 63;
    const int eg  = tid >> 6;            // 0..3
    const int dt  = blockIdx.x;          // 0..15
    const int b   = blockIdx.y;          // 0..15
    const int d   = dt * 64 + dl;

    __shared__ float cs[DD];
    ((float4*)cs)[tid] = ((const float4*)(ctx + (size_t)b * DD))[tid];
    __syncthreads();

    float acc = 0.f;
    const float* Wp = W + (size_t)(eg * 256) * DD + d;
    const float* cp = cs + eg * 256;
#pragma unroll 8
    for (int e = 0; e < 256; ++e)
        acc = fmaf(cp[e], Wp[(size_t)e * DD], acc);

    __shared__ float red[256];
    red[tid] = acc;
    __syncthreads();
    if (tid < 64)
        ctil[b * DD + d] = red[tid] + red[64 + tid] + red[128 + tid] + red[192 + tid];
}

// ---------------------------------------------------------------------------
// Kernel 2: fused score + online-softmax + weighted accumulation, one pass
// over values. grid (NCHUNK, B), 256 threads = 4 waves. Each wave keeps
// running (m, l, o[1024]) with o spread 16 f32/lane as 4x float4.
// ---------------------------------------------------------------------------
template <int NCHUNK>
__global__ __launch_bounds__(256)
void flash_kernel(const float* __restrict__ values,
                  const float* __restrict__ ctil,
                  float* __restrict__ partials) {
    constexpr int ROWS = SD / NCHUNK;
    const int chunk = blockIdx.x;
    const int b     = blockIdx.y;
    const int r0    = chunk * ROWS;
    const int tid   = threadIdx.x;
    const int wave  = tid >> 6;
    const int lane  = tid & 63;

    const float4* ct4 = (const float4*)(ctil + (size_t)b * DD);
    const float4 c0 = ct4[lane];
    const float4 c1 = ct4[64 + lane];
    const float4 c2 = ct4[128 + lane];
    const float4 c3 = ct4[192 + lane];

    float4 o0 = {0.f, 0.f, 0.f, 0.f}, o1 = o0, o2 = o0, o3 = o0;
    float m = -1e30f, l = 0.f;

#pragma unroll 2
    for (int i = wave; i < ROWS; i += 4) {
        const float4* v4 = (const float4*)(values + ((size_t)b * SD + r0 + i) * DD);
        float4 v0 = v4[lane];
        float4 v1 = v4[64 + lane];
        float4 v2 = v4[128 + lane];
        float4 v3 = v4[192 + lane];

        float s = dot4(v0, c0) + dot4(v1, c1) + dot4(v2, c2) + dot4(v3, c3);
#pragma unroll
        for (int off = 32; off > 0; off >>= 1) s += __shfl_xor(s, off, 64);

        if (s > m) {
            float corr = exp2f((m - s) * L2E);
            m = s;
            l *= corr;
            mul4(o0, corr); mul4(o1, corr); mul4(o2, corr); mul4(o3, corr);
        }
        float p = exp2f((s - m) * L2E);
        l += p;
        fma4(o0, p, v0); fma4(o1, p, v1); fma4(o2, p, v2); fma4(o3, p, v3);
    }

    // ---- combine the 4 waves' partials ----
    __shared__ float red_m[4];
    __shared__ float red_l[4];
    __shared__ float4 obuf[4][256];

    if (lane == 0) { red_m[wave] = m; red_l[wave] = l; }
    __syncthreads();

    const float M = fmaxf(fmaxf(red_m[0], red_m[1]), fmaxf(red_m[2], red_m[3]));
    const float Lb =
        red_l[0] * exp2f((red_m[0] - M) * L2E) +
        red_l[1] * exp2f((red_m[1] - M) * L2E) +
        red_l[2] * exp2f((red_m[2] - M) * L2E) +
        red_l[3] * exp2f((red_m[3] - M) * L2E);

    const float corr = exp2f((m - M) * L2E);  // wave-uniform
    mul4(o0, corr); mul4(o1, corr); mul4(o2, corr); mul4(o3, corr);

    obuf[wave][lane]       = o0;
    obuf[wave][64 + lane]  = o1;
    obuf[wave][128 + lane] = o2;
    obuf[wave][192 + lane] = o3;
    __syncthreads();

    float4 t = obuf[0][tid];
    add4(t, obuf[1][tid]); add4(t, obuf[2][tid]); add4(t, obuf[3][tid]);

    float* part = partials + (size_t)(b * NCHUNK + chunk) * PREC;
    ((float4*)part)[tid] = t;
    if (tid == 0) { part[1024] = M; part[1025] = Lb; }
}

// ---------------------------------------------------------------------------
// Kernel 3: combine NCHUNK partials -> out[b,:]. grid (4 d-tiles, B),
// 256 threads; lane-parallel M/L reduction, fully-unrolled weighted sum.
// ---------------------------------------------------------------------------
template <int NCHUNK>
__global__ __launch_bounds__(256)
void finalize_kernel(const float* __restrict__ partials,
                     float* __restrict__ out) {
    constexpr int CPL = NCHUNK / 64;  // chunks per lane (wave 0)
    const int dt  = blockIdx.x;       // 0..3
    const int b   = blockIdx.y;       // 0..15
    const int tid = threadIdx.x;
    const float* base = partials + (size_t)b * NCHUNK * PREC;

    __shared__ float corr_s[NCHUNK];
    __shared__ float L_s;

    if (tid < 64) {
        const int lane = tid;
        float mv[CPL], lv[CPL];
        float mm = -1e30f;
#pragma unroll
        for (int j = 0; j < CPL; ++j) {
            mv[j] = base[(size_t)(lane * CPL + j) * PREC + 1024];
            lv[j] = base[(size_t)(lane * CPL + j) * PREC + 1025];
            mm = fmaxf(mm, mv[j]);
        }
#pragma unroll
        for (int off = 32; off > 0; off >>= 1) mm = fmaxf(mm, __shfl_xor(mm, off, 64));
        float lp = 0.f;
#pragma unroll
        for (int j = 0; j < CPL; ++j) {
            float c = exp2f((mv[j] - mm) * L2E);
            corr_s[lane * CPL + j] = c;
            lp = fmaf(c, lv[j], lp);
        }
#pragma unroll
        for (int off = 32; off > 0; off >>= 1) lp += __shfl_xor(lp, off, 64);
        if (lane == 0) L_s = lp;
    }
    __syncthreads();

    const float inv = 1.0f / L_s;
    const int d = dt * 256 + tid;
    float acc = 0.f;
#pragma unroll 16
    for (int i = 0; i < NCHUNK; ++i)
        acc = fmaf(corr_s[i], base[(size_t)i * PREC + d], acc);
    out[(size_t)b * DD + d] = acc * inv;
}

// ---------------------------------------------------------------------------
extern "C" void kernel_launch(void* const* d_in, const int* in_sizes, int n_in,
                              void* d_out, int out_size, void* d_ws, size_t ws_size,
                              hipStream_t stream) {
    const float* values = (const float*)d_in[0];   // [B,S,D]
    const float* ctx    = (const float*)d_in[1];   // [B,D]
    const float* W      = (const float*)d_in[2];   // [D,D]
    float* out = (float*)d_out;                    // [B,D] f32

    float* ctil     = (float*)d_ws;                // B*D floats
    float* partials = ctil + (size_t)BD * DD;      // B*NCHUNK*PREC floats

    ctx_proj_kernel<<<dim3(16, BD), 256, 0, stream>>>(ctx, W, ctil);

    const size_t fixed = (size_t)BD * DD * 4;
    if (fixed + (size_t)BD * 128 * PREC * 4 <= ws_size) {
        flash_kernel<128><<<dim3(128, BD), 256, 0, stream>>>(values, ctil, partials);
        finalize_kernel<128><<<dim3(4, BD), 256, 0, stream>>>(partials, out);
    } else {
        flash_kernel<64><<<dim3(64, BD), 256, 0, stream>>>(values, ctil, partials);
        finalize_kernel<64><<<dim3(4, BD), 256, 0, stream>>>(partials, out);
    }
}

// Round 3
// 60.986 us; speedup vs baseline: 1.6692x; 1.2090x over previous
//
#include <hip/hip_runtime.h>
#include <cstdint>
#include <cstddef>

#define BD 16
#define SD 4096
#define DD 1024
#define L2E 1.4426950408889634f
#define PREC 1028   // floats per partial record: 1024 o + m + l + pad
#define NCHUNK 64

typedef float f32x4 __attribute__((ext_vector_type(4)));

__device__ __forceinline__ float dot4(f32x4 a, f32x4 b) {
    return fmaf(a.x, b.x, fmaf(a.y, b.y, fmaf(a.z, b.z, a.w * b.w)));
}

// ---------------------------------------------------------------------------
// Kernel 1: ctil[b,d] = sum_e ctx[b,e] * W[e,d]  (bias dropped: softmax-shift
// invariant). grid (4 d-tiles, 16 b, 4 e-slices) = 256 blocks, 256 threads =
// 64 d-lanes (float4 each) x 4 sub-e-groups. float4 W loads (1KB/instr).
// Partial merge via atomicAdd into zeroed ctil.
// ---------------------------------------------------------------------------
__global__ __launch_bounds__(256)
void ctx_proj_kernel(const float* __restrict__ ctx,
                     const float* __restrict__ W,
                     float* __restrict__ ctil) {
    const int tid = threadIdx.x;
    const int dl  = tid & 63;            // float4 column group
    const int eg  = tid >> 6;            // 0..3 sub-e-group
    const int dt  = blockIdx.x;          // 0..3
    const int b   = blockIdx.y;          // 0..15
    const int ez  = blockIdx.z;          // 0..3
    const int d4  = dt * 256 + dl * 4;

    __shared__ float cs[256];
    cs[tid] = ctx[b * DD + ez * 256 + tid];
    __syncthreads();

    f32x4 acc = {0.f, 0.f, 0.f, 0.f};
    const float* cp = cs + eg * 64;
    const float* Wp = W + (size_t)(ez * 256 + eg * 64) * DD + d4;
#pragma unroll 8
    for (int e = 0; e < 64; ++e) {
        f32x4 w = *(const f32x4*)(Wp + (size_t)e * DD);
        acc += cp[e] * w;
    }

    __shared__ f32x4 red[256];
    red[tid] = acc;
    __syncthreads();
    if (tid < 64) {
        f32x4 r = red[tid] + red[64 + tid] + red[128 + tid] + red[192 + tid];
        float* dst = ctil + b * DD + d4;
        atomicAdd(dst + 0, r.x);
        atomicAdd(dst + 1, r.y);
        atomicAdd(dst + 2, r.z);
        atomicAdd(dst + 3, r.w);
    }
}

// ---------------------------------------------------------------------------
// Kernel 2: fused score + online-softmax + weighted accumulation, one pass
// over values. grid (NCHUNK, B) = 1024 blocks x 4 waves = 16 waves/CU
// (matches the 4-waves/SIMD cap at this VGPR count). Nontemporal value loads.
// ---------------------------------------------------------------------------
__global__ __launch_bounds__(256)
void flash_kernel(const float* __restrict__ values,
                  const float* __restrict__ ctil,
                  float* __restrict__ partials) {
    constexpr int ROWS = SD / NCHUNK;
    const int chunk = blockIdx.x;
    const int b     = blockIdx.y;
    const int r0    = chunk * ROWS;
    const int tid   = threadIdx.x;
    const int wave  = tid >> 6;
    const int lane  = tid & 63;

    const f32x4* ct4 = (const f32x4*)(ctil + (size_t)b * DD);
    const f32x4 c0 = ct4[lane];
    const f32x4 c1 = ct4[64 + lane];
    const f32x4 c2 = ct4[128 + lane];
    const f32x4 c3 = ct4[192 + lane];

    f32x4 o0 = {0.f, 0.f, 0.f, 0.f}, o1 = o0, o2 = o0, o3 = o0;
    float m = -1e30f, l = 0.f;

#pragma unroll 2
    for (int i = wave; i < ROWS; i += 4) {
        const f32x4* v4 = (const f32x4*)(values + ((size_t)b * SD + r0 + i) * DD);
        f32x4 v0 = __builtin_nontemporal_load(v4 + lane);
        f32x4 v1 = __builtin_nontemporal_load(v4 + 64 + lane);
        f32x4 v2 = __builtin_nontemporal_load(v4 + 128 + lane);
        f32x4 v3 = __builtin_nontemporal_load(v4 + 192 + lane);

        float s = dot4(v0, c0) + dot4(v1, c1) + dot4(v2, c2) + dot4(v3, c3);
#pragma unroll
        for (int off = 32; off > 0; off >>= 1) s += __shfl_xor(s, off, 64);

        if (s > m) {   // wave-uniform branch, rarely taken after warm-up
            float corr = exp2f((m - s) * L2E);
            m = s;
            l *= corr;
            o0 *= corr; o1 *= corr; o2 *= corr; o3 *= corr;
        }
        float p = exp2f((s - m) * L2E);
        l += p;
        o0 += p * v0; o1 += p * v1; o2 += p * v2; o3 += p * v3;
    }

    // ---- combine the 4 waves' partials ----
    __shared__ float red_m[4];
    __shared__ float red_l[4];
    __shared__ f32x4 obuf[4][256];

    if (lane == 0) { red_m[wave] = m; red_l[wave] = l; }
    __syncthreads();

    const float M = fmaxf(fmaxf(red_m[0], red_m[1]), fmaxf(red_m[2], red_m[3]));
    const float Lb =
        red_l[0] * exp2f((red_m[0] - M) * L2E) +
        red_l[1] * exp2f((red_m[1] - M) * L2E) +
        red_l[2] * exp2f((red_m[2] - M) * L2E) +
        red_l[3] * exp2f((red_m[3] - M) * L2E);

    const float corr = exp2f((m - M) * L2E);  // wave-uniform
    o0 *= corr; o1 *= corr; o2 *= corr; o3 *= corr;

    obuf[wave][lane]       = o0;
    obuf[wave][64 + lane]  = o1;
    obuf[wave][128 + lane] = o2;
    obuf[wave][192 + lane] = o3;
    __syncthreads();

    f32x4 t = obuf[0][tid] + obuf[1][tid] + obuf[2][tid] + obuf[3][tid];

    float* part = partials + (size_t)(b * NCHUNK + chunk) * PREC;
    ((f32x4*)part)[tid] = t;
    if (tid == 0) { part[1024] = M; part[1025] = Lb; }
}

// ---------------------------------------------------------------------------
// Kernel 3: combine NCHUNK partials -> out[b,:]. grid (4 d-tiles, B).
// ---------------------------------------------------------------------------
__global__ __launch_bounds__(256)
void finalize_kernel(const float* __restrict__ partials,
                     float* __restrict__ out) {
    const int dt  = blockIdx.x;       // 0..3
    const int b   = blockIdx.y;       // 0..15
    const int tid = threadIdx.x;
    const float* base = partials + (size_t)b * NCHUNK * PREC;

    __shared__ float corr_s[NCHUNK];
    __shared__ float L_s;

    if (tid < 64) {
        const int lane = tid;
        float mv = base[(size_t)lane * PREC + 1024];
        float lv = base[(size_t)lane * PREC + 1025];
        float mm = mv;
#pragma unroll
        for (int off = 32; off > 0; off >>= 1) mm = fmaxf(mm, __shfl_xor(mm, off, 64));
        float c = exp2f((mv - mm) * L2E);
        corr_s[lane] = c;
        float lp = c * lv;
#pragma unroll
        for (int off = 32; off > 0; off >>= 1) lp += __shfl_xor(lp, off, 64);
        if (lane == 0) L_s = lp;
    }
    __syncthreads();

    const float inv = 1.0f / L_s;
    const int d = dt * 256 + tid;
    float acc = 0.f;
#pragma unroll 16
    for (int i = 0; i < NCHUNK; ++i)
        acc = fmaf(corr_s[i], base[(size_t)i * PREC + d], acc);
    out[(size_t)b * DD + d] = acc * inv;
}

// ---------------------------------------------------------------------------
extern "C" void kernel_launch(void* const* d_in, const int* in_sizes, int n_in,
                              void* d_out, int out_size, void* d_ws, size_t ws_size,
                              hipStream_t stream) {
    const float* values = (const float*)d_in[0];   // [B,S,D]
    const float* ctx    = (const float*)d_in[1];   // [B,D]
    const float* W      = (const float*)d_in[2];   // [D,D]
    float* out = (float*)d_out;                    // [B,D] f32

    float* ctil     = (float*)d_ws;                // B*D floats
    float* partials = ctil + (size_t)BD * DD;      // B*NCHUNK*PREC floats

    hipMemsetAsync(ctil, 0, (size_t)BD * DD * sizeof(float), stream);
    ctx_proj_kernel<<<dim3(4, BD, 4), 256, 0, stream>>>(ctx, W, ctil);
    flash_kernel<<<dim3(NCHUNK, BD), 256, 0, stream>>>(values, ctil, partials);
    finalize_kernel<<<dim3(4, BD), 256, 0, stream>>>(partials, out);
}